// Round 1
// baseline (299.195 us; speedup 1.0000x reference)
//
#include <hip/hip_runtime.h>

typedef __bf16 bf16x8 __attribute__((ext_vector_type(8)));
typedef float f32x4 __attribute__((ext_vector_type(4)));

#define HH 64
#define WW 64
#define CIN 256
#define COUT 256
#define HW 4096
#define BSTRIDE 296   // 9 taps * 32 ch + 8 pad (bf16 elements); 592 B, 16B-aligned

// ---------------------------------------------------------------------------
// Kernel 1: blend circle weights, cast to bf16, store pre-fragmented A layout:
//   global K index = (c>>5)*288 + tap*32 + (c&31);  kstep ksg = K/32
//   element for (o, K) lives at wp[(((ksg*16 + o/16)*64 + lane)*8) + j]
//   with lane = (o&15) | ((kk>>3)<<4), j = kk&7, kk = K&31
// so an MFMA a-frag is one contiguous 16B load per lane.
// ---------------------------------------------------------------------------
__global__ __launch_bounds__(256) void prep_weights(const float* __restrict__ weight,
                                                    __bf16* __restrict__ wp) {
    const int o = blockIdx.x;
    const int c = threadIdx.x;
    const float* w = weight + (o * 256 + c) * 9;
    float t0 = w[0], t1 = w[1], t2 = w[2], t3 = w[3], t4 = w[4],
          t5 = w[5], t6 = w[6], t7 = w[7], t8 = w[8];
    const float Af = 0.7071067811865476f;
    const float Bf = 1.0f - Af;
    float r[9];
    r[0] = Af * (Af * t0 + Bf * t1) + Bf * (Af * t3 + Bf * t4);
    r[1] = t1;
    r[2] = Af * (Bf * t1 + Af * t2) + Bf * (Bf * t4 + Af * t5);
    r[3] = t3;
    r[4] = t4;
    r[5] = t5;
    r[6] = Bf * (Af * t3 + Bf * t4) + Af * (Af * t6 + Bf * t7);
    r[7] = t7;
    r[8] = Bf * (Bf * t4 + Af * t5) + Af * (Bf * t7 + Af * t8);

    const int cg = c >> 5;        // channel group 0..7
    const int cl = c & 31;        // channel within group
    const int tm = o >> 4, rr = o & 15;
    const int lane = rr | ((cl >> 3) << 4);
    const int j = cl & 7;
    #pragma unroll
    for (int tap = 0; tap < 9; ++tap) {
        int ksg = cg * 9 + tap;                       // global kstep 0..71
        wp[((((ksg * 16 + tm) << 6) | lane) << 3) | j] = (__bf16)r[tap];
    }
}

// ---------------------------------------------------------------------------
// Kernel 2: fused bilinear-sample + implicit GEMM.
// Block: 256 thr (4 waves). Tile M=128 (mb half of Cout) x N=64 (one image row).
// Per channel-group (32 ch): build Bs[64 px][9*32] once, 9 MFMA ksteps reuse it.
// ---------------------------------------------------------------------------
__global__ __launch_bounds__(256, 2) void dcn_main(
        const float* __restrict__ x, const float* __restrict__ off,
        const float* __restrict__ msk, const __bf16* __restrict__ wp,
        const float* __restrict__ bias, float* __restrict__ out) {
    __shared__ __bf16 Bs[64 * BSTRIDE];   // 37888 B

    const int tid = threadIdx.x;
    const int wv = tid >> 6;
    const int lane = tid & 63;

    // XCD-aware swizzle: 8 XCDs round-robin on blockIdx; give each batch image
    // to 2 XCDs so x[b] (4 MB) stays L2-resident.
    const int bid = blockIdx.x;
    const int xcd = bid & 7;
    const int g = bid >> 3;                  // 0..63
    const int b = xcd >> 1;                  // batch 0..3
    const int u = ((xcd & 1) << 6) | g;      // 0..127
    const int mb = u >> 6;                   // M half 0..1
    const int h = u & 63;                    // image row
    const int wx = lane;                     // pixel column (lane == pixel)

    const int q = lane >> 4, rr = lane & 15;
    const int pixoff = h * 64 + wx;
    const float* xb = x + (size_t)b * CIN * HW;
    const float* offb = off + (size_t)b * 18 * HW + pixoff;
    const float* mskb = msk + (size_t)b * 9 * HW + pixoff;

    f32x4 acc[2][4];
    #pragma unroll
    for (int i = 0; i < 2; ++i)
        #pragma unroll
        for (int jj = 0; jj < 4; ++jj)
            acc[i][jj] = (f32x4)0.0f;

    const int tmg0 = mb * 8 + wv * 2;        // this wave's first m-tile (of 16)

    for (int cg = 0; cg < 8; ++cg) {
        __syncthreads();   // previous ksteps done reading Bs
        // ---------------- build Bs for 32 channels x 9 taps -----------------
        const int cbase = cg * 32;
        #pragma unroll 1
        for (int tap = 0; tap < 9; ++tap) {
            const int ki = tap / 3, kj = tap - 3 * ki;
            float dy = offb[(2 * tap) * HW];
            float dx = offb[(2 * tap + 1) * HW];
            float mv = mskb[tap * HW];
            float py = (float)(h - 1 + ki) + dy;
            float px = (float)(wx - 1 + kj) + dx;
            float y0f = floorf(py), x0f = floorf(px);
            float ly = py - y0f, lx = px - x0f;
            float hy = 1.0f - ly, hx = 1.0f - lx;
            int y0 = (int)y0f, x0 = (int)x0f;
            int y1 = y0 + 1, x1 = x0 + 1;
            bool vy0 = (y0 >= 0) && (y0 < HH);
            bool vy1 = (y1 >= 0) && (y1 < HH);
            bool vx0 = (x0 >= 0) && (x0 < WW);
            bool vx1 = (x1 >= 0) && (x1 < WW);
            int cy0 = y0 < 0 ? 0 : (y0 > HH - 1 ? HH - 1 : y0);
            int cy1 = y1 < 0 ? 0 : (y1 > HH - 1 ? HH - 1 : y1);
            int cx0 = x0 < 0 ? 0 : (x0 > WW - 1 ? WW - 1 : x0);
            int cx1 = x1 < 0 ? 0 : (x1 > WW - 1 ? WW - 1 : x1);
            int i00 = cy0 * WW + cx0, i01 = cy0 * WW + cx1;
            int i10 = cy1 * WW + cx0, i11 = cy1 * WW + cx1;
            float w00 = (vy0 && vx0) ? hy * hx * mv : 0.0f;
            float w01 = (vy0 && vx1) ? hy * lx * mv : 0.0f;
            float w10 = (vy1 && vx0) ? ly * hx * mv : 0.0f;
            float w11 = (vy1 && vx1) ? ly * lx * mv : 0.0f;

            const float* xp = xb + (size_t)(cbase + wv * 8) * HW;
            bf16x8 p0;
            #pragma unroll
            for (int j = 0; j < 8; ++j) {
                float v = w00 * xp[i00] + w01 * xp[i01]
                        + w10 * xp[i10] + w11 * xp[i11];
                p0[j] = (__bf16)v;
                xp += HW;
            }
            *(bf16x8*)&Bs[lane * BSTRIDE + tap * 32 + wv * 8] = p0;
        }
        __syncthreads();
        // ---------------- 9 MFMA ksteps over this group ---------------------
        const __bf16* ap = wp + (((size_t)((cg * 9) * 16 + tmg0) * 64 + lane) << 3);
        bf16x8 a0 = *(const bf16x8*)ap;
        bf16x8 a1 = *(const bf16x8*)(ap + 512);
        #pragma unroll 1
        for (int kl = 0; kl < 9; ++kl) {
            bf16x8 na0 = a0, na1 = a1;
            if (kl < 8) {                       // prefetch next kstep's A frags
                const __bf16* np = ap + 8192;
                na0 = *(const bf16x8*)np;
                na1 = *(const bf16x8*)(np + 512);
            }
            const int kcol = kl * 32 + q * 8;
            bf16x8 bb0 = *(const bf16x8*)&Bs[(0 + rr) * BSTRIDE + kcol];
            bf16x8 bb1 = *(const bf16x8*)&Bs[(16 + rr) * BSTRIDE + kcol];
            bf16x8 bb2 = *(const bf16x8*)&Bs[(32 + rr) * BSTRIDE + kcol];
            bf16x8 bb3 = *(const bf16x8*)&Bs[(48 + rr) * BSTRIDE + kcol];
            acc[0][0] = __builtin_amdgcn_mfma_f32_16x16x32_bf16(a0, bb0, acc[0][0], 0, 0, 0);
            acc[1][0] = __builtin_amdgcn_mfma_f32_16x16x32_bf16(a1, bb0, acc[1][0], 0, 0, 0);
            acc[0][1] = __builtin_amdgcn_mfma_f32_16x16x32_bf16(a0, bb1, acc[0][1], 0, 0, 0);
            acc[1][1] = __builtin_amdgcn_mfma_f32_16x16x32_bf16(a1, bb1, acc[1][1], 0, 0, 0);
            acc[0][2] = __builtin_amdgcn_mfma_f32_16x16x32_bf16(a0, bb2, acc[0][2], 0, 0, 0);
            acc[1][2] = __builtin_amdgcn_mfma_f32_16x16x32_bf16(a1, bb2, acc[1][2], 0, 0, 0);
            acc[0][3] = __builtin_amdgcn_mfma_f32_16x16x32_bf16(a0, bb3, acc[0][3], 0, 0, 0);
            acc[1][3] = __builtin_amdgcn_mfma_f32_16x16x32_bf16(a1, bb3, acc[1][3], 0, 0, 0);
            ap += 8192;
            a0 = na0;
            a1 = na1;
        }
    }

    // ------------------------------ epilogue -------------------------------
    // C/D layout (16x16x32): col = lane&15, row = (lane>>4)*4 + reg
    const int mbase = mb * 128 + wv * 32;
    #pragma unroll
    for (int tm = 0; tm < 2; ++tm) {
        #pragma unroll
        for (int i = 0; i < 4; ++i) {
            const int m = mbase + tm * 16 + q * 4 + i;
            const float bv = bias[m];
            float* op = out + ((size_t)b * COUT + m) * HW + h * 64;
            #pragma unroll
            for (int tn = 0; tn < 4; ++tn) {
                op[tn * 16 + rr] = acc[tm][tn][i] + bv;
            }
        }
    }
}

extern "C" void kernel_launch(void* const* d_in, const int* in_sizes, int n_in,
                              void* d_out, int out_size, void* d_ws, size_t ws_size,
                              hipStream_t stream) {
    const float* x      = (const float*)d_in[0];   // [4,256,64,64]
    const float* off    = (const float*)d_in[1];   // [4,18,64,64]
    const float* msk    = (const float*)d_in[2];   // [4,9,64,64]
    const float* weight = (const float*)d_in[3];   // [256,256,3,3]
    const float* bias   = (const float*)d_in[4];   // [256]
    float* out = (float*)d_out;                    // [4,256,64,64]

    __bf16* wp = (__bf16*)d_ws;                    // 589824 bf16 = 1.18 MB

    prep_weights<<<256, 256, 0, stream>>>(weight, wp);
    dcn_main<<<512, 256, 0, stream>>>(x, off, msk, wp, bias, out);
}

// Round 2
// 136.083 us; speedup vs baseline: 2.1986x; 2.1986x over previous
//
#include <hip/hip_runtime.h>

typedef __bf16 bf16x8 __attribute__((ext_vector_type(8)));
typedef float f32x4 __attribute__((ext_vector_type(4)));

#define HH 64
#define WW 64
#define CIN 256
#define COUT 256
#define HW 4096
#define BSTRIDE 296   // Bs row stride (bf16 elems) = 592 B
#define NROWS 12      // staged input rows [rowbase, rowbase+11]
#define XROW 65       // px slots per staged row (64 + 1 pad -> odd stride)

// ---------------------------------------------------------------------------
// Kernel 1: blend circle weights -> bf16, pre-fragmented MFMA A layout.
//   wp[(ksg*16 + tm)*64 + lane][0..7], ksg = (c>>5)*9 + tap, lane = (o&15)|(q<<4),
//   element j covers channel-in-group q*8+j.  Each thread emits 9 full 16B
//   fragments (b128 stores) for one (o, channel-octet) pair.
// ---------------------------------------------------------------------------
__global__ __launch_bounds__(256) void prep_weights(const float* __restrict__ weight,
                                                    __bf16* __restrict__ wp) {
    const int idx = blockIdx.x * 256 + threadIdx.x;   // 0..8191
    const int o   = idx >> 5;                         // 0..255
    const int g8  = idx & 31;                         // channel octet
    const int cg  = g8 >> 2, q = g8 & 3;
    const int c0  = cg * 32 + q * 8;
    const int tm  = o >> 4, rr = o & 15;
    const int lane = rr | (q << 4);
    const float Af = 0.70710678118654752f;
    const float Bf = 1.0f - Af;
    float r[9][8];
    #pragma unroll
    for (int j = 0; j < 8; ++j) {
        const float* w = weight + ((size_t)o * 256 + c0 + j) * 9;
        float t0=w[0],t1=w[1],t2=w[2],t3=w[3],t4=w[4],t5=w[5],t6=w[6],t7=w[7],t8=w[8];
        r[0][j] = Af*(Af*t0+Bf*t1) + Bf*(Af*t3+Bf*t4);
        r[1][j] = t1; r[3][j] = t3; r[4][j] = t4; r[5][j] = t5; r[7][j] = t7;
        r[2][j] = Af*(Bf*t1+Af*t2) + Bf*(Bf*t4+Af*t5);
        r[6][j] = Bf*(Af*t3+Bf*t4) + Af*(Af*t6+Bf*t7);
        r[8][j] = Bf*(Bf*t4+Af*t5) + Af*(Bf*t7+Af*t8);
    }
    #pragma unroll
    for (int tap = 0; tap < 9; ++tap) {
        int ksg = cg * 9 + tap;
        bf16x8 v;
        #pragma unroll
        for (int j = 0; j < 8; ++j) v[j] = (__bf16)r[tap][j];
        *(bf16x8*)&wp[(size_t)(((ksg * 16 + tm) << 6) | lane) << 3] = v;
    }
}

// ---------------------------------------------------------------------------
// Kernel 2: fused LDS-staged bilinear-sample + implicit GEMM.
// Block: 512 thr (8 waves), tile M=256 (all Cout) x N=64 (one image row).
// Per cg (32 ch), two halves of 16 ch: stage 12 rows into Xs (bf16, 8-ch
// interleaved), gather 4 corners per (px,tap,8ch) as ds_read_b128, write Bs.
// Then 9 MFMA ksteps over the cg.
// ---------------------------------------------------------------------------
__global__ __launch_bounds__(512, 2) void dcn_main(
        const float* __restrict__ x, const float* __restrict__ off,
        const float* __restrict__ msk, const __bf16* __restrict__ wp,
        const float* __restrict__ bias, float* __restrict__ out) {
    __shared__ __bf16 Bs[64 * BSTRIDE];            // 37888 B
    __shared__ __bf16 Xs[2 * NROWS * XROW * 8];    // 24960 B  (total 62848 B)

    const int tid  = threadIdx.x;
    const int wv   = tid >> 6;
    const int lane = tid & 63;
    const int q    = lane >> 4, rr = lane & 15;
    const int px   = tid & 63;    // sampling pixel (column)
    const int c0   = wv;          // unit combo base 0..7

    // 256 blocks; bid&7 ~ XCD. 2 XCDs per batch image for L2 locality.
    const int bid = blockIdx.x;
    const int xcd = bid & 7;
    const int r_  = bid >> 3;                 // 0..31
    const int b   = xcd >> 1;
    const int h   = ((xcd & 1) << 5) | r_;    // 0..63

    const int rowbase = min(max(h - 5, 0), HH - NROWS);
    const float* xb = x + (size_t)b * CIN * HW;

    // ---- per-thread bilinear unit params, computed ONCE (<=3 units) -------
    // unit c = c0 + 8k, c<18: sg = c/9 (local 8-ch subgroup), tap = c%9
    float W00[3], W01[3], W10[3], W11[3];
    int AY0[3], AY1[3], DXO[3], COLB[3], GP[3];
    #pragma unroll
    for (int k = 0; k < 3; ++k) {
        int c = c0 + k * 8;
        if (c < 18) {
            int sg = c / 9, tap = c % 9;
            int ki = tap / 3, kj = tap - 3 * ki;
            const float* offp = off + (size_t)b * 18 * HW + h * 64 + px;
            float dy = offp[(2 * tap) * HW];
            float dx = offp[(2 * tap + 1) * HW];
            float mv = msk[(size_t)b * 9 * HW + (size_t)tap * HW + h * 64 + px];
            float py  = (float)(h - 1 + ki) + dy;
            float pxf = (float)(px - 1 + kj) + dx;
            float y0f = floorf(py), x0f = floorf(pxf);
            float ly = py - y0f, lx = pxf - x0f;
            float hy = 1.0f - ly, hx = 1.0f - lx;
            int y0 = (int)y0f, x0 = (int)x0f;
            int y1 = y0 + 1, x1 = x0 + 1;
            bool vy0 = (y0 >= 0) && (y0 < HH), vy1 = (y1 >= 0) && (y1 < HH);
            bool vx0 = (x0 >= 0) && (x0 < WW), vx1 = (x1 >= 0) && (x1 < WW);
            int cy0 = min(max(y0, 0), HH - 1), cy1 = min(max(y1, 0), HH - 1);
            int cx0 = min(max(x0, 0), WW - 1), cx1 = min(max(x1, 0), WW - 1);
            W00[k] = (vy0 && vx0) ? hy * hx * mv : 0.0f;
            W01[k] = (vy0 && vx1) ? hy * lx * mv : 0.0f;
            W10[k] = (vy1 && vx0) ? ly * hx * mv : 0.0f;
            W11[k] = (vy1 && vx1) ? ly * lx * mv : 0.0f;
            int ry0 = min(max(cy0 - rowbase, 0), NROWS - 1);
            int ry1 = min(max(cy1 - rowbase, 0), NROWS - 1);
            bool useG = (vy0 && (cy0 < rowbase || cy0 > rowbase + NROWS - 1))
                     || (vy1 && (cy1 < rowbase || cy1 > rowbase + NROWS - 1));
            AY0[k]  = ((sg * NROWS + ry0) * XROW + cx0) * 16;   // byte addr in Xs
            AY1[k]  = ((sg * NROWS + ry1) * XROW + cx0) * 16;
            DXO[k]  = (cx1 - cx0) * 16;                          // 0 or 16
            COLB[k] = (tap * 32 + sg * 8) * 2;                   // Bs byte col
            GP[k]   = cy0 | (cy1 << 6) | (cx0 << 12) | (cx1 << 18) | (sg << 24)
                    | (useG ? (1u << 31) : 0);
        }
    }

    f32x4 acc[2][4];
    #pragma unroll
    for (int i = 0; i < 2; ++i)
        #pragma unroll
        for (int jj = 0; jj < 4; ++jj)
            acc[i][jj] = (f32x4)0.0f;

    const char* XsB = (const char*)Xs;
    char* BsB = (char*)Bs;

    for (int cg = 0; cg < 8; ++cg) {
        #pragma unroll
        for (int half = 0; half < 2; ++half) {
            __syncthreads();   // Xs free (prev gathers done) / Bs free (prev MFMA done)
            // ---- stage 16 channels x 12 rows into Xs (bf16, 8-ch interleave)
            {
                const int ch = tid >> 5;          // 0..15
                const int p5 = tid & 31;
                const int sg = ch >> 3, c8 = ch & 7;
                const float* xc = xb + (size_t)(cg * 32 + half * 16 + ch) * HW
                                + rowbase * 64;
                #pragma unroll
                for (int k = 0; k < 24; ++k) {
                    int linear = k * 32 + p5;          // 0..767
                    float f = xc[linear];
                    int row = linear >> 6, ppx = linear & 63;
                    Xs[(((sg * NROWS + row) * XROW + ppx) << 3) + c8] = (__bf16)f;
                }
            }
            __syncthreads();
            // ---- gather: each thread does its <=3 (px,tap,sg) units --------
            #pragma unroll
            for (int k = 0; k < 3; ++k) {
                int c = c0 + k * 8;
                if (c < 18) {
                    bf16x8 c00 = *(const bf16x8*)(XsB + AY0[k]);
                    bf16x8 c01 = *(const bf16x8*)(XsB + AY0[k] + DXO[k]);
                    bf16x8 c10 = *(const bf16x8*)(XsB + AY1[k]);
                    bf16x8 c11 = *(const bf16x8*)(XsB + AY1[k] + DXO[k]);
                    float w0 = W00[k], w1 = W01[k], w2 = W10[k], w3 = W11[k];
                    bf16x8 res;
                    #pragma unroll
                    for (int j = 0; j < 8; ++j) {
                        float v = w0 * (float)c00[j] + w1 * (float)c01[j]
                                + w2 * (float)c10[j] + w3 * (float)c11[j];
                        res[j] = (__bf16)v;
                    }
                    int gp = GP[k];
                    if (gp < 0) {   // rare: a valid corner fell outside staged rows
                        int cy0 = gp & 63, cy1 = (gp >> 6) & 63;
                        int cx0 = (gp >> 12) & 63, cx1 = (gp >> 18) & 63;
                        int sg = (gp >> 24) & 3;
                        const float* xc = xb + (size_t)(cg * 32 + half * 16 + sg * 8) * HW;
                        int i00 = cy0 * 64 + cx0, i01 = cy0 * 64 + cx1;
                        int i10 = cy1 * 64 + cx0, i11 = cy1 * 64 + cx1;
                        #pragma unroll
                        for (int j = 0; j < 8; ++j) {
                            float v = w0 * xc[i00] + w1 * xc[i01]
                                    + w2 * xc[i10] + w3 * xc[i11];
                            res[j] = (__bf16)v;
                            xc += HW;
                        }
                    }
                    *(bf16x8*)(BsB + px * 592 + COLB[k] + half * 32) = res;
                }
            }
        }
        __syncthreads();
        // ---- 9 MFMA ksteps over this channel group ------------------------
        const __bf16* ap = wp + (((size_t)(cg * 9) * 16 + wv * 2) * 64 + lane) * 8;
        bf16x8 a0 = *(const bf16x8*)ap;
        bf16x8 a1 = *(const bf16x8*)(ap + 512);
        #pragma unroll 1
        for (int kl = 0; kl < 9; ++kl) {
            bf16x8 na0 = a0, na1 = a1;
            if (kl < 8) {
                const __bf16* np = ap + 8192;
                na0 = *(const bf16x8*)np;
                na1 = *(const bf16x8*)(np + 512);
            }
            const int kcol = kl * 32 + q * 8;
            bf16x8 bb0 = *(const bf16x8*)&Bs[(0  + rr) * BSTRIDE + kcol];
            bf16x8 bb1 = *(const bf16x8*)&Bs[(16 + rr) * BSTRIDE + kcol];
            bf16x8 bb2 = *(const bf16x8*)&Bs[(32 + rr) * BSTRIDE + kcol];
            bf16x8 bb3 = *(const bf16x8*)&Bs[(48 + rr) * BSTRIDE + kcol];
            acc[0][0] = __builtin_amdgcn_mfma_f32_16x16x32_bf16(a0, bb0, acc[0][0], 0, 0, 0);
            acc[1][0] = __builtin_amdgcn_mfma_f32_16x16x32_bf16(a1, bb0, acc[1][0], 0, 0, 0);
            acc[0][1] = __builtin_amdgcn_mfma_f32_16x16x32_bf16(a0, bb1, acc[0][1], 0, 0, 0);
            acc[1][1] = __builtin_amdgcn_mfma_f32_16x16x32_bf16(a1, bb1, acc[1][1], 0, 0, 0);
            acc[0][2] = __builtin_amdgcn_mfma_f32_16x16x32_bf16(a0, bb2, acc[0][2], 0, 0, 0);
            acc[1][2] = __builtin_amdgcn_mfma_f32_16x16x32_bf16(a1, bb2, acc[1][2], 0, 0, 0);
            acc[0][3] = __builtin_amdgcn_mfma_f32_16x16x32_bf16(a0, bb3, acc[0][3], 0, 0, 0);
            acc[1][3] = __builtin_amdgcn_mfma_f32_16x16x32_bf16(a1, bb3, acc[1][3], 0, 0, 0);
            ap += 8192;
            a0 = na0;
            a1 = na1;
        }
    }

    // ------------------------------ epilogue -------------------------------
    // C/D layout (16x16x32): col = lane&15, row = (lane>>4)*4 + reg
    const int mbase = wv * 32;
    #pragma unroll
    for (int tm = 0; tm < 2; ++tm) {
        #pragma unroll
        for (int i = 0; i < 4; ++i) {
            const int m = mbase + tm * 16 + q * 4 + i;
            const float bv = bias[m];
            float* op = out + ((size_t)b * COUT + m) * HW + h * 64;
            #pragma unroll
            for (int tn = 0; tn < 4; ++tn) {
                op[tn * 16 + rr] = acc[tm][tn][i] + bv;
            }
        }
    }
}

extern "C" void kernel_launch(void* const* d_in, const int* in_sizes, int n_in,
                              void* d_out, int out_size, void* d_ws, size_t ws_size,
                              hipStream_t stream) {
    const float* x      = (const float*)d_in[0];   // [4,256,64,64]
    const float* off    = (const float*)d_in[1];   // [4,18,64,64]
    const float* msk    = (const float*)d_in[2];   // [4,9,64,64]
    const float* weight = (const float*)d_in[3];   // [256,256,3,3]
    const float* bias   = (const float*)d_in[4];   // [256]
    float* out = (float*)d_out;                    // [4,256,64,64]

    __bf16* wp = (__bf16*)d_ws;                    // 589824 bf16 = 1.18 MB

    prep_weights<<<32, 256, 0, stream>>>(weight, wp);
    dcn_main<<<256, 512, 0, stream>>>(x, off, msk, wp, bias, out);
}

// Round 3
// 131.607 us; speedup vs baseline: 2.2734x; 1.0340x over previous
//
#include <hip/hip_runtime.h>

typedef __bf16 bf16x8 __attribute__((ext_vector_type(8)));
typedef float f32x4 __attribute__((ext_vector_type(4)));

#define HH 64
#define WW 64
#define CIN 256
#define COUT 256
#define HW 4096
#define BSTRIDE 296   // Bs row stride (bf16 elems) = 592 B
#define NROWS 12      // staged input rows [rowbase, rowbase+11]
#define XROW 65       // px slots per staged row (64 + 1 pad -> odd stride)
#define XS_OFF 37888  // byte offset of Xs inside smem

// Raw barrier: flush LDS (lgkmcnt) but do NOT drain vmcnt — staging global
// loads stay in flight across the barrier (the compiler waits at their uses).
__device__ __forceinline__ void bar_sync() {
    asm volatile("s_waitcnt lgkmcnt(0)" ::: "memory");
    __builtin_amdgcn_s_barrier();
    asm volatile("" ::: "memory");
}

// ---------------------------------------------------------------------------
// Kernel 1: blend circle weights -> bf16, pre-fragmented MFMA A layout.
// Tap-parallel: 288 blocks x 256 thr; thread = (tap, cg, tm, lane) emits ONE
// 16B fragment. tap is block-uniform (8192 threads per tap, 256 | 8192).
// ---------------------------------------------------------------------------
__global__ __launch_bounds__(256) void prep_weights(const float* __restrict__ weight,
                                                    __bf16* __restrict__ wp) {
    const int t = blockIdx.x * 256 + threadIdx.x;
    const int lane = t & 63;
    const int tm   = (t >> 6) & 15;
    const int cg   = (t >> 10) & 7;
    const int tap  = t >> 13;              // 0..8, block-uniform
    const int rr = lane & 15, q = lane >> 4;
    const int o  = tm * 16 + rr;
    const int c0 = cg * 32 + q * 8;
    const float* wb = weight + ((size_t)o * 256 + c0) * 9;
    const float Af = 0.70710678118654752f;
    const float Bf = 1.0f - Af;
    bf16x8 v;
    #pragma unroll
    for (int j = 0; j < 8; ++j) {
        const float* w = wb + j * 9;
        float r;
        switch (tap) {
            case 0:  r = Af*(Af*w[0]+Bf*w[1]) + Bf*(Af*w[3]+Bf*w[4]); break;
            case 1:  r = w[1]; break;
            case 2:  r = Af*(Bf*w[1]+Af*w[2]) + Bf*(Bf*w[4]+Af*w[5]); break;
            case 3:  r = w[3]; break;
            case 4:  r = w[4]; break;
            case 5:  r = w[5]; break;
            case 6:  r = Bf*(Af*w[3]+Bf*w[4]) + Af*(Af*w[6]+Bf*w[7]); break;
            case 7:  r = w[7]; break;
            default: r = Bf*(Bf*w[4]+Af*w[5]) + Af*(Bf*w[7]+Af*w[8]); break;
        }
        v[j] = (__bf16)r;
    }
    const int ksg = cg * 9 + tap;
    *(bf16x8*)&wp[(size_t)(((ksg * 16 + tm) << 6) | lane) << 3] = v;
}

// ---------------------------------------------------------------------------
// Kernel 2: pipelined LDS-staged bilinear-sample + implicit GEMM.
// 256 blocks x 512 thr (8 waves). Tile M=256 x N=64 (one image row).
// Pipeline over 16 stages (cg,half): write Xs from regs, issue next stage's
// global loads, gather -> Bs, MFMA per cg with kl split across wave halves.
// ---------------------------------------------------------------------------
__global__ __launch_bounds__(512, 2) void dcn_main(
        const float* __restrict__ x, const float* __restrict__ off,
        const float* __restrict__ msk, const __bf16* __restrict__ wp,
        const float* __restrict__ bias, float* __restrict__ out) {
    __shared__ char smem[65536];   // Bs[0..37887] | Xs[37888..62847]; epilogue: f32 scratch
    __bf16* Bs = (__bf16*)smem;
    __bf16* Xs = (__bf16*)(smem + XS_OFF);
    char* BsB  = smem;
    const char* XsB = (const char*)(smem + XS_OFF);

    const int tid  = threadIdx.x;
    const int wv   = tid >> 6;
    const int lane = tid & 63;
    const int q    = lane >> 4, rr = lane & 15;
    const int px   = lane;                 // sampling pixel column
    const int ch   = tid >> 5;             // staging channel 0..15
    const int p5   = tid & 31;
    const int sgch = ch >> 3, c8 = ch & 7;

    const int bid = blockIdx.x;
    const int xcd = bid & 7;
    const int r_  = bid >> 3;
    const int b   = xcd >> 1;
    const int h   = ((xcd & 1) << 5) | r_;

    const int rowbase = min(max(h - 5, 0), HH - NROWS);
    const float* xb = x + (size_t)b * CIN * HW;

    // ---- per-thread gather-unit params, computed ONCE ---------------------
    // unit c (0..17): k=0 -> c=wv; k=1 -> c=wv+8; k=2 -> c=wv+10 (waves 6,7).
    float W00[3], W01[3], W10[3], W11[3];
    int AY0[3], AY1[3], DXO[3], COLB[3], GP[3];
    bool UV[3];
    #pragma unroll
    for (int k = 0; k < 3; ++k) {
        int c = (k < 2) ? (wv + 8 * k) : ((wv >= 6) ? wv + 10 : -1);
        UV[k] = (c >= 0);
        if (UV[k]) {
            int sg = c / 9, tap = c % 9;
            int ki = tap / 3, kj = tap - 3 * ki;
            const float* offp = off + (size_t)b * 18 * HW + h * 64 + px;
            float dy = offp[(2 * tap) * HW];
            float dx = offp[(2 * tap + 1) * HW];
            float mv = msk[(size_t)b * 9 * HW + (size_t)tap * HW + h * 64 + px];
            float py  = (float)(h - 1 + ki) + dy;
            float pxf = (float)(px - 1 + kj) + dx;
            float y0f = floorf(py), x0f = floorf(pxf);
            float ly = py - y0f, lx = pxf - x0f;
            float hy = 1.0f - ly, hx = 1.0f - lx;
            int y0 = (int)y0f, x0 = (int)x0f;
            int y1 = y0 + 1, x1 = x0 + 1;
            bool vy0 = (y0 >= 0) && (y0 < HH), vy1 = (y1 >= 0) && (y1 < HH);
            bool vx0 = (x0 >= 0) && (x0 < WW), vx1 = (x1 >= 0) && (x1 < WW);
            int cy0 = min(max(y0, 0), HH - 1), cy1 = min(max(y1, 0), HH - 1);
            int cx0 = min(max(x0, 0), WW - 1), cx1 = min(max(x1, 0), WW - 1);
            W00[k] = (vy0 && vx0) ? hy * hx * mv : 0.0f;
            W01[k] = (vy0 && vx1) ? hy * lx * mv : 0.0f;
            W10[k] = (vy1 && vx0) ? ly * hx * mv : 0.0f;
            W11[k] = (vy1 && vx1) ? ly * lx * mv : 0.0f;
            int ry0 = min(max(cy0 - rowbase, 0), NROWS - 1);
            int ry1 = min(max(cy1 - rowbase, 0), NROWS - 1);
            bool useG = (vy0 && (cy0 < rowbase || cy0 > rowbase + NROWS - 1))
                     || (vy1 && (cy1 < rowbase || cy1 > rowbase + NROWS - 1));
            AY0[k]  = ((sg * NROWS + ry0) * XROW + cx0) * 16;
            AY1[k]  = ((sg * NROWS + ry1) * XROW + cx0) * 16;
            DXO[k]  = (cx1 - cx0) * 16;
            COLB[k] = (tap * 32 + sg * 8) * 2;
            GP[k]   = cy0 | (cy1 << 6) | (cx0 << 12) | (cx1 << 18) | (sg << 24)
                    | (useG ? (1u << 31) : 0);
        }
    }

    f32x4 acc[4][4];
    #pragma unroll
    for (int i = 0; i < 4; ++i)
        #pragma unroll
        for (int n = 0; n < 4; ++n)
            acc[i][n] = (f32x4)0.0f;

    const int tm0   = (wv & 3) * 4;
    const int klbeg = (wv & 4) ? 5 : 0;
    const int nkl   = (wv & 4) ? 4 : 5;

    // ---- preload stage 0 staging values into regs -------------------------
    float R[24];
    {
        const float* xc = xb + (size_t)ch * HW + rowbase * 64 + p5;
        #pragma unroll
        for (int k = 0; k < 24; ++k) R[k] = xc[k * 32];
    }

    for (int s = 0; s < 16; ++s) {
        const int cg = s >> 1, half = s & 1;
        bar_sync();   // Xs(s-1) gathers done; Bs free after MFMA(cg-1)
        // ---- write Xs from regs ------------------------------------------
        #pragma unroll
        for (int k = 0; k < 24; ++k) {
            int linear = k * 32 + p5;
            int row = linear >> 6, ppx = linear & 63;
            Xs[(((sgch * NROWS + row) * XROW + ppx) << 3) + c8] = (__bf16)R[k];
        }
        // ---- issue next stage's global loads (in flight across barriers) --
        if (s < 15) {
            const int s1 = s + 1;
            const float* xc = xb + (size_t)(((s1 >> 1) * 32 + (s1 & 1) * 16) + ch) * HW
                            + rowbase * 64 + p5;
            #pragma unroll
            for (int k = 0; k < 24; ++k) R[k] = xc[k * 32];
        }
        bar_sync();   // Xs ready
        // ---- gather: <=3 (c,px) units per thread -------------------------
        #pragma unroll
        for (int k = 0; k < 3; ++k) {
            if (UV[k]) {
                bf16x8 c00 = *(const bf16x8*)(XsB + AY0[k]);
                bf16x8 c01 = *(const bf16x8*)(XsB + AY0[k] + DXO[k]);
                bf16x8 c10 = *(const bf16x8*)(XsB + AY1[k]);
                bf16x8 c11 = *(const bf16x8*)(XsB + AY1[k] + DXO[k]);
                float w0 = W00[k], w1 = W01[k], w2 = W10[k], w3 = W11[k];
                bf16x8 res;
                #pragma unroll
                for (int j = 0; j < 8; ++j) {
                    float v = w0 * (float)c00[j] + w1 * (float)c01[j]
                            + w2 * (float)c10[j] + w3 * (float)c11[j];
                    res[j] = (__bf16)v;
                }
                int gp = GP[k];
                if (gp < 0) {   // rare: valid corner outside staged rows
                    int cy0 = gp & 63, cy1 = (gp >> 6) & 63;
                    int cx0 = (gp >> 12) & 63, cx1 = (gp >> 18) & 63;
                    int sg = (gp >> 24) & 3;
                    const float* xc = xb + (size_t)(cg * 32 + half * 16 + sg * 8) * HW;
                    int i00 = cy0 * 64 + cx0, i01 = cy0 * 64 + cx1;
                    int i10 = cy1 * 64 + cx0, i11 = cy1 * 64 + cx1;
                    #pragma unroll
                    for (int j = 0; j < 8; ++j) {
                        float v = w0 * xc[i00] + w1 * xc[i01]
                                + w2 * xc[i10] + w3 * xc[i11];
                        res[j] = (__bf16)v;
                        xc += HW;
                    }
                }
                *(bf16x8*)(BsB + px * 592 + COLB[k] + half * 32) = res;
            }
        }
        if (half) {
            bar_sync();   // Bs complete (both halves)
            // ---- MFMA: M=64/wave, kl split across wave halves -------------
            const __bf16* ap = wp + ((size_t)((cg * 9 + klbeg) * 16 + tm0) * 64 + lane) * 8;
            bf16x8 a0 = *(const bf16x8*)ap;
            bf16x8 a1 = *(const bf16x8*)(ap + 512);
            bf16x8 a2 = *(const bf16x8*)(ap + 1024);
            bf16x8 a3 = *(const bf16x8*)(ap + 1536);
            int kc = (klbeg * 32 + q * 8) * 2;   // byte col in Bs row
            #pragma unroll 1
            for (int t = 0; t < nkl; ++t) {
                bf16x8 n0 = a0, n1 = a1, n2 = a2, n3 = a3;
                if (t + 1 < nkl) {
                    const __bf16* np = ap + 8192;
                    n0 = *(const bf16x8*)np;
                    n1 = *(const bf16x8*)(np + 512);
                    n2 = *(const bf16x8*)(np + 1024);
                    n3 = *(const bf16x8*)(np + 1536);
                }
                const char* bp = BsB + rr * 592 + kc;
                bf16x8 bb0 = *(const bf16x8*)(bp);
                bf16x8 bb1 = *(const bf16x8*)(bp + 16 * 592);
                bf16x8 bb2 = *(const bf16x8*)(bp + 32 * 592);
                bf16x8 bb3 = *(const bf16x8*)(bp + 48 * 592);
                acc[0][0] = __builtin_amdgcn_mfma_f32_16x16x32_bf16(a0, bb0, acc[0][0], 0, 0, 0);
                acc[1][0] = __builtin_amdgcn_mfma_f32_16x16x32_bf16(a1, bb0, acc[1][0], 0, 0, 0);
                acc[2][0] = __builtin_amdgcn_mfma_f32_16x16x32_bf16(a2, bb0, acc[2][0], 0, 0, 0);
                acc[3][0] = __builtin_amdgcn_mfma_f32_16x16x32_bf16(a3, bb0, acc[3][0], 0, 0, 0);
                acc[0][1] = __builtin_amdgcn_mfma_f32_16x16x32_bf16(a0, bb1, acc[0][1], 0, 0, 0);
                acc[1][1] = __builtin_amdgcn_mfma_f32_16x16x32_bf16(a1, bb1, acc[1][1], 0, 0, 0);
                acc[2][1] = __builtin_amdgcn_mfma_f32_16x16x32_bf16(a2, bb1, acc[2][1], 0, 0, 0);
                acc[3][1] = __builtin_amdgcn_mfma_f32_16x16x32_bf16(a3, bb1, acc[3][1], 0, 0, 0);
                acc[0][2] = __builtin_amdgcn_mfma_f32_16x16x32_bf16(a0, bb2, acc[0][2], 0, 0, 0);
                acc[1][2] = __builtin_amdgcn_mfma_f32_16x16x32_bf16(a1, bb2, acc[1][2], 0, 0, 0);
                acc[2][2] = __builtin_amdgcn_mfma_f32_16x16x32_bf16(a2, bb2, acc[2][2], 0, 0, 0);
                acc[3][2] = __builtin_amdgcn_mfma_f32_16x16x32_bf16(a3, bb2, acc[3][2], 0, 0, 0);
                acc[0][3] = __builtin_amdgcn_mfma_f32_16x16x32_bf16(a0, bb3, acc[0][3], 0, 0, 0);
                acc[1][3] = __builtin_amdgcn_mfma_f32_16x16x32_bf16(a1, bb3, acc[1][3], 0, 0, 0);
                acc[2][3] = __builtin_amdgcn_mfma_f32_16x16x32_bf16(a2, bb3, acc[2][3], 0, 0, 0);
                acc[3][3] = __builtin_amdgcn_mfma_f32_16x16x32_bf16(a3, bb3, acc[3][3], 0, 0, 0);
                ap += 8192;
                kc += 64;
                a0 = n0; a1 = n1; a2 = n2; a3 = n3;
            }
        }
    }

    // ---- epilogue: cross-wave kl-partial reduce via LDS, then store -------
    float* scr = (float*)smem;   // Bs/Xs dead now
    bar_sync();
    if (wv >= 4) {
        const int base = (wv - 4) * 4096 + lane * 4;
        #pragma unroll
        for (int i = 0; i < 4; ++i)
            #pragma unroll
            for (int n = 0; n < 4; ++n)
                *(f32x4*)&scr[base + (i * 4 + n) * 256] = acc[i][n];
    }
    bar_sync();
    if (wv < 4) {
        const int mrow = wv * 64;
        const int base = wv * 4096 + lane * 4;
        #pragma unroll
        for (int i = 0; i < 4; ++i) {
            #pragma unroll
            for (int n = 0; n < 4; ++n) {
                f32x4 p = *(const f32x4*)&scr[base + (i * 4 + n) * 256];
                #pragma unroll
                for (int e = 0; e < 4; ++e) {
                    int m = mrow + i * 16 + q * 4 + e;
                    out[((size_t)b * COUT + m) * HW + h * 64 + n * 16 + rr]
                        = acc[i][n][e] + p[e] + bias[m];
                }
            }
        }
    }
}

extern "C" void kernel_launch(void* const* d_in, const int* in_sizes, int n_in,
                              void* d_out, int out_size, void* d_ws, size_t ws_size,
                              hipStream_t stream) {
    const float* x      = (const float*)d_in[0];   // [4,256,64,64]
    const float* off    = (const float*)d_in[1];   // [4,18,64,64]
    const float* msk    = (const float*)d_in[2];   // [4,9,64,64]
    const float* weight = (const float*)d_in[3];   // [256,256,3,3]
    const float* bias   = (const float*)d_in[4];   // [256]
    float* out = (float*)d_out;                    // [4,256,64,64]

    __bf16* wp = (__bf16*)d_ws;                    // 589824 bf16 = 1.18 MB

    prep_weights<<<288, 256, 0, stream>>>(weight, wp);
    dcn_main<<<256, 512, 0, stream>>>(x, off, msk, wp, bias, out);
}